// Round 15
// baseline (187.378 us; speedup 1.0000x reference)
//
#include <hip/hip_runtime.h>

// GCN:  w'_e = dinv[row]*w*dinv[col]  (folded norm, shared by BOTH layers);
//   g = X@W unscaled (MFMA bf16);  out[c] = relu(dinv[c]^2*g[c] + sum w'*g[row] + b)
//
// R15: G stored as 4 FEATURE PLANES of 16 features (3.2MB each -- fits a
// per-XCD 4MB L2).  agg_kernel makes plane the SLOW blockIdx dim: the chip
// processes ~one plane at a time, so the random row gathers become
// L2-resident (latency ~200cy, 34TB/s) instead of L3 (~400-900cy).  Same
// per-thread instruction/byte counts; descriptors re-stream 4x (cheap).
// aggmm keeps concurrent planes (MFMA needs all 64 feats) -- address only.
// Session facts: global atomic ~62B memory-side; 64M LDS atomics = 445us;
// gathers latency-bound (R9 counters: nothing saturated); 32KB LDS cap.

#define BNODES 512
#define LB 9
#define MAXBKT 256
#define EPT 12
#define EPB (256 * EPT)

typedef __attribute__((ext_vector_type(8))) short bf16x8;
typedef __attribute__((ext_vector_type(8))) unsigned short u16x8;
typedef __attribute__((ext_vector_type(8))) float f32x8;
typedef __attribute__((ext_vector_type(4))) float f32x4;

__device__ __forceinline__ unsigned short f2bf(float f) {
    unsigned u = __float_as_uint(f);
    u = (u + 0x7FFF + ((u >> 16) & 1)) >> 16;   // rtne
    return (unsigned short)u;
}
__device__ __forceinline__ float bf2f(unsigned short h) {
    return __uint_as_float(((unsigned)h) << 16);
}
__device__ __forceinline__ f32x8 bf8tof(u16x8 u) {
    f32x8 r;
    #pragma unroll
    for (int i = 0; i < 8; ++i) r[i] = bf2f(u[i]);
    return r;
}

__device__ __forceinline__ int waveIncScan(int v, int lane) {
    #pragma unroll
    for (int d = 1; d < 64; d <<= 1) {
        int u = __shfl_up(v, d, 64);
        if (lane >= d) v += u;
    }
    return v;
}

template<int NW>
__device__ __forceinline__ int blockIncScan(int v, int t, int* wt) {
    int lane = t & 63, w = t >> 6;
    int s = waveIncScan(v, lane);
    if (lane == 63) wt[w] = s;
    __syncthreads();
    int add = 0;
    #pragma unroll
    for (int i = 0; i < NW - 1; ++i) if (i < w) add += wt[i];
    return s + add;
}

// gather over a 16-ushort-stride plane: rows at Gp + rw*16 + off8 (u16x8).
__device__ __forceinline__ f32x8 gather8p(
    const unsigned short* __restrict__ Gp, const int2* __restrict__ sedge,
    int s, int m, int off8, f32x8 a0)
{
    f32x8 a1 = (f32x8)0.f;
    int e = s, e_end = s + m;
    if ((((unsigned long long)(sedge + e)) & 8) && e < e_end) {
        int2 pk = sedge[e++];
        float w = __int_as_float(pk.y);
        a0 += w * bf8tof(*(const u16x8*)&Gp[(size_t)pk.x * 16 + off8]);
    }
    for (; e + 1 < e_end; e += 2) {
        int4 pp = *(const int4*)&sedge[e];
        float w0 = __int_as_float(pp.y);
        float w1 = __int_as_float(pp.w);
        u16x8 g0 = *(const u16x8*)&Gp[(size_t)pp.x * 16 + off8];
        u16x8 g1 = *(const u16x8*)&Gp[(size_t)pp.z * 16 + off8];
        a0 += w0 * bf8tof(g0);
        a1 += w1 * bf8tof(g1);
    }
    if (e < e_end) {
        int2 pk = sedge[e];
        float w = __int_as_float(pk.y);
        a0 += w * bf8tof(*(const u16x8*)&Gp[(size_t)pk.x * 16 + off8]);
    }
    return a0 + a1;
}

// ---- hist (+ weight transpose in tail blocks) ----------------------------

__global__ __launch_bounds__(256) void hist_kernel(
    const int* __restrict__ col, int* __restrict__ H, int E, int NBKT,
    const float* __restrict__ W1, const float* __restrict__ W2,
    unsigned short* __restrict__ WT1, unsigned short* __restrict__ WT2, int NEB)
{
    int t = threadIdx.x, blk = blockIdx.x;
    if (blk >= NEB) {
        int i = (blk - NEB) * 256 + t;
        if (i < 64 * 128) {
            int c = i >> 7, k = i & 127;
            WT1[i] = f2bf(W1[k * 64 + c]);
        } else if (i < 64 * 128 + 64 * 64) {
            int j = i - 64 * 128;
            int c = j >> 6, k = j & 63;
            WT2[j] = f2bf(W2[k * 64 + c]);
        }
        return;
    }
    __shared__ int h[MAXBKT];
    for (int b = t; b < NBKT; b += 256) h[b] = 0;
    __syncthreads();
    int base = blk * EPB;
    #pragma unroll
    for (int i = 0; i < EPT; ++i) {
        int e = base + i * 256 + t;
        if (e < E) atomicAdd(&h[col[e] >> LB], 1);
    }
    __syncthreads();
    for (int b = t; b < NBKT; b += 256) H[blk * NBKT + b] = h[b];
}

__global__ __launch_bounds__(512) void rowscan_kernel(
    int* __restrict__ H, int* __restrict__ rowSum, int NEB, int NBKT)
{
    __shared__ int wt[8];
    int b = blockIdx.x, t = threadIdx.x;
    int v = (t < NEB) ? H[t * NBKT + b] : 0;
    int incl = blockIncScan<8>(v, t, wt);
    if (t < NEB) H[t * NBKT + b] = incl - v;
    if (t == 511) rowSum[b] = incl;
}

// ---- merged (LDS-sorted scatter) + (layer-1 MFMA GEMM, plane output) -----
__global__ __launch_bounds__(256) void scatter_gemm_kernel(
    const int* __restrict__ row, const int* __restrict__ col,
    const float* __restrict__ w, const int* __restrict__ H,
    const int* __restrict__ rowSum, int2* __restrict__ sedge1,
    int E, int NBKT, int NEB,
    const float* __restrict__ X, const unsigned short* __restrict__ WT,
    unsigned short* __restrict__ G, int n, int np16)
{
    __shared__ __align__(16) char smem[32768];
    const int t = threadIdx.x;
    const int blk = blockIdx.x;

    if (blk < NEB) {
        int2* stage = (int2*)smem;
        unsigned char* bstage = (unsigned char*)(stage + EPB);
        int* lcnt  = (int*)(bstage + EPB);
        int* loff  = lcnt + MAXBKT;
        int* lcur  = loff + MAXBKT;
        int* gbase = lcur + MAXBKT;
        int* wt    = gbase + MAXBKT;

        int vb = (t < NBKT) ? rowSum[t] : 0;
        int ib = blockIncScan<4>(vb, t, wt);
        if (t < NBKT) gbase[t] = (ib - vb) + H[blk * NBKT + t];
        for (int b = t; b < NBKT; b += 256) lcnt[b] = 0;
        __syncthreads();

        int base = blk * EPB;
        #pragma unroll
        for (int i = 0; i < EPT; ++i) {
            int e = base + i * 256 + t;
            if (e < E) atomicAdd(&lcnt[col[e] >> LB], 1);
        }
        __syncthreads();
        int v = (t < NBKT) ? lcnt[t] : 0;
        int incl = blockIncScan<4>(v, t, wt);
        if (t < NBKT) {
            int x0 = incl - v;
            loff[t] = x0;
            lcur[t] = x0;
        }
        __syncthreads();
        #pragma unroll
        for (int i = 0; i < EPT; ++i) {
            int e = base + i * 256 + t;
            if (e < E) {
                int c = col[e];
                int b = c >> LB;
                int pos = atomicAdd(&lcur[b], 1);    // LDS atomic
                int2 pk;
                pk.x = row[e] | ((c & (BNODES - 1)) << 20);
                pk.y = __float_as_int(w[e]);
                stage[pos] = pk;
                bstage[pos] = (unsigned char)b;
            }
        }
        __syncthreads();
        int ecnt = E - base; if (ecnt > EPB) ecnt = EPB;
        for (int i = t; i < ecnt; i += 256) {
            int b = bstage[i];
            int g = gbase[b] + (i - loff[b]);
            sedge1[g] = stage[i];
        }
        return;
    }

    constexpr int K = 128, ROWB = 256, SLOTS = 16, CPR = 32;
    char* xs = smem;
    char* ws = smem + 64 * ROWB;
    const int nodeBase = (blk - NEB) * 64;

    for (int q = t; q < 64 * SLOTS; q += 256) {
        int r = q / SLOTS, s = q % SLOTS;
        uint4 v = *(const uint4*)(WT + r * K + s * 8);
        *(uint4*)(ws + r * ROWB + ((s ^ (r & 7)) * 16)) = v;
    }
    for (int q = t; q < 64 * CPR; q += 256) {
        int r = q / CPR, c = q % CPR;
        int node = nodeBase + r;
        float4 v = make_float4(0.f, 0.f, 0.f, 0.f);
        if (node < n) v = *(const float4*)(X + (size_t)node * K + c * 4);
        ushort4 h;
        h.x = f2bf(v.x); h.y = f2bf(v.y); h.z = f2bf(v.z); h.w = f2bf(v.w);
        *(ushort4*)(xs + r * ROWB + (((c >> 1) ^ (r & 7)) * 16) + (c & 1) * 8) = h;
    }
    __syncthreads();

    const int lane = t & 63;
    const int wv = t >> 6;
    const int lr = lane & 15;
    const int lk = lane >> 4;
    const int arow = (wv << 4) + lr;

    f32x4 acc[4] = {};
    #pragma unroll
    for (int kb = 0; kb < 4; ++kb) {
        int s = kb * 4 + lk;
        bf16x8 a = *(bf16x8*)(xs + arow * ROWB + ((s ^ (arow & 7)) * 16));
        #pragma unroll
        for (int cb = 0; cb < 4; ++cb) {
            int c = cb * 16 + lr;
            bf16x8 b = *(bf16x8*)(ws + c * ROWB + ((s ^ (c & 7)) * 16));
            acc[cb] = __builtin_amdgcn_mfma_f32_16x16x32_bf16(a, b, acc[cb], 0, 0, 0);
        }
    }

    // plane layout: G[plane cb][node][16]
    int rowbase = nodeBase + (wv << 4) + (lk << 2);
    #pragma unroll
    for (int j = 0; j < 4; ++j) {
        int node = rowbase + j;
        if (node >= n) continue;
        #pragma unroll
        for (int cb = 0; cb < 4; ++cb)
            G[(size_t)cb * np16 + (size_t)node * 16 + lr] = f2bf(acc[cb][j]);
    }
}

// ---- fine_dinv: per-bucket degree + scan -> nodeStart/nodeCnt/dinv -------
__global__ __launch_bounds__(512) void fine_dinv_kernel(
    const int2* __restrict__ sedge1, const int* __restrict__ rowSum,
    int* __restrict__ nodeStart, int* __restrict__ nodeCnt,
    float* __restrict__ dinv, int n, int NBKT)
{
    __shared__ int cnt[BNODES];
    __shared__ float wsum[BNODES];
    __shared__ int bs[MAXBKT + 1];
    __shared__ int wt[8];
    int b = blockIdx.x, t = threadIdx.x;

    int vb = (t < NBKT) ? rowSum[t] : 0;
    int ib = blockIncScan<8>(vb, t, wt);
    if (t < NBKT) bs[t] = ib - vb;
    if (t == 511) bs[NBKT] = ib;
    cnt[t] = 0; wsum[t] = 1.0f;
    __syncthreads();

    int s = bs[b], e = bs[b + 1];
    for (int j = s + t; j < e; j += 512) {
        int2 pk = sedge1[j];
        int ld = pk.x >> 20;
        atomicAdd(&cnt[ld], 1);
        atomicAdd(&wsum[ld], __int_as_float(pk.y));
    }
    __syncthreads();
    int v = cnt[t];
    int incl = blockIncScan<8>(v, t, wt);
    int x0 = s + incl - v;
    int node = b * BNODES + t;
    if (node < n) {
        nodeStart[node] = x0;
        nodeCnt[node] = v;
        dinv[node] = rsqrtf(wsum[t]);
    }
}

// ---- fine_csr: CSR scatter with folded weights w' = dinv[row]*w*dinv[col] -
__global__ __launch_bounds__(512) void fine_csr_kernel(
    const int2* __restrict__ sedge1, const int* __restrict__ rowSum,
    const int* __restrict__ nodeStart, const float* __restrict__ dinv,
    int2* __restrict__ sedge2, int n, int NBKT)
{
    __shared__ int cur[BNODES];
    __shared__ float dloc[BNODES];
    __shared__ int bs[MAXBKT + 1];
    __shared__ int wt[8];
    int b = blockIdx.x, t = threadIdx.x;

    int vb = (t < NBKT) ? rowSum[t] : 0;
    int ib = blockIncScan<8>(vb, t, wt);
    if (t < NBKT) bs[t] = ib - vb;
    if (t == 511) bs[NBKT] = ib;
    int node = b * BNODES + t;
    cur[t]  = (node < n) ? nodeStart[node] : 0;
    dloc[t] = (node < n) ? dinv[node] : 0.f;
    __syncthreads();

    int s = bs[b], e = bs[b + 1];
    for (int j = s + t; j < e; j += 512) {
        int2 pk = sedge1[j];
        int ld = pk.x >> 20;
        int rw = pk.x & 0xFFFFF;
        int pos = atomicAdd(&cur[ld], 1);            // LDS atomic
        float wp = __int_as_float(pk.y) * dinv[rw] * dloc[ld];
        sedge2[pos] = make_int2(rw, __float_as_int(wp));
    }
}

// ---- FUSED agg1 + gemm2, 32 nodes/block (concurrent planes) --------------
__global__ __launch_bounds__(256) void aggmm_kernel(
    const unsigned short* __restrict__ G1, const int2* __restrict__ sedge2,
    const int* __restrict__ nodeStart, const int* __restrict__ nodeCnt,
    const float* __restrict__ dinv, const float* __restrict__ bias,
    const unsigned short* __restrict__ WT2, unsigned short* __restrict__ G2,
    int n, int np16)
{
    constexpr int BN = 32;
    constexpr int ROWB = 128;
    __shared__ char smem[(BN + 64) * ROWB];   // act (4KB) | ws (8KB)
    char* xs = smem;
    char* ws = smem + BN * ROWB;
    const int tid = threadIdx.x;
    const int nodeBase = blockIdx.x * BN;

    for (int q = tid; q < 64 * 8; q += 256) {
        int r = q >> 3, s = q & 7;
        uint4 v = *(const uint4*)(WT2 + r * 64 + s * 8);
        *(uint4*)(ws + r * ROWB + ((s ^ (r & 7)) * 16)) = v;
    }

    int p8 = tid & 7;
    int r = tid >> 3;
    int node = nodeBase + r;
    const unsigned short* Gp = G1 + (size_t)(p8 >> 1) * np16;
    const int off8 = (p8 & 1) * 8;
    f32x8 o = (f32x8)0.f;
    if (node < n) {
        float di = dinv[node];
        f32x8 a = (di * di) * bf8tof(*(const u16x8*)&Gp[(size_t)node * 16 + off8]);
        a = gather8p(Gp, sedge2, nodeStart[node], nodeCnt[node], off8, a);
        #pragma unroll
        for (int i = 0; i < 8; ++i)
            o[i] = fmaxf(a[i] + bias[p8 * 8 + i], 0.f);
    }
    u16x8 h;
    #pragma unroll
    for (int i = 0; i < 8; ++i) h[i] = f2bf(o[i]);
    *(u16x8*)(xs + r * ROWB + ((p8 ^ (r & 7)) * 16)) = h;
    __syncthreads();

    const int lane = tid & 63;
    const int w = tid >> 6;
    const int lr = lane & 15;
    const int lk = lane >> 4;
    const int rb = w >> 1;
    const int arow = rb * 16 + lr;

    f32x4 acc[2] = {};
    #pragma unroll
    for (int kb = 0; kb < 2; ++kb) {
        int s = kb * 4 + lk;
        bf16x8 a = *(bf16x8*)(xs + arow * ROWB + ((s ^ (arow & 7)) * 16));
        #pragma unroll
        for (int cc = 0; cc < 2; ++cc) {
            int c = ((w & 1) * 2 + cc) * 16 + lr;
            bf16x8 b = *(bf16x8*)(ws + c * ROWB + ((s ^ (c & 7)) * 16));
            acc[cc] = __builtin_amdgcn_mfma_f32_16x16x32_bf16(a, b, acc[cc], 0, 0, 0);
        }
    }

    // g2 written UNSCALED, plane layout
    int rowbase = nodeBase + rb * 16 + (lk << 2);
    #pragma unroll
    for (int j = 0; j < 4; ++j) {
        int nd = rowbase + j;
        if (nd >= n) continue;
        #pragma unroll
        for (int cc = 0; cc < 2; ++cc) {
            int plane = (w & 1) * 2 + cc;
            G2[(size_t)plane * np16 + (size_t)nd * 16 + lr] = f2bf(acc[cc][j]);
        }
    }
}

// ---- final aggregation: PLANE-SLICED (plane = slow blockIdx dim) ---------
// 256 threads = 128 nodes x 2 lanes; each pass reads only a 3.2MB plane.
__global__ __launch_bounds__(256) void agg_kernel(
    const unsigned short* __restrict__ G, const int2* __restrict__ sedge2,
    const int* __restrict__ nodeStart, const int* __restrict__ nodeCnt,
    const float* __restrict__ dinv, const float* __restrict__ bias,
    float* __restrict__ OUT, int n, int np16, int NBN)
{
    int p  = blockIdx.x / NBN;          // plane 0..3 (slow dim)
    int nb = blockIdx.x % NBN;
    int node = nb * 128 + (threadIdx.x >> 1);
    if (node >= n) return;
    int h = threadIdx.x & 1;
    const int off8 = h * 8;
    const unsigned short* Gp = G + (size_t)p * np16;

    float di = dinv[node];
    f32x8 a = (di * di) * bf8tof(*(const u16x8*)&Gp[(size_t)node * 16 + off8]);
    a = gather8p(Gp, sedge2, nodeStart[node], nodeCnt[node], off8, a);

    int fb = p * 16 + off8;
    float4 o0, o1;
    o0.x = fmaxf(a[0] + bias[fb + 0], 0.f);
    o0.y = fmaxf(a[1] + bias[fb + 1], 0.f);
    o0.z = fmaxf(a[2] + bias[fb + 2], 0.f);
    o0.w = fmaxf(a[3] + bias[fb + 3], 0.f);
    o1.x = fmaxf(a[4] + bias[fb + 4], 0.f);
    o1.y = fmaxf(a[5] + bias[fb + 5], 0.f);
    o1.z = fmaxf(a[6] + bias[fb + 6], 0.f);
    o1.w = fmaxf(a[7] + bias[fb + 7], 0.f);
    *(float4*)&OUT[(size_t)node * 64 + fb] = o0;
    *(float4*)&OUT[(size_t)node * 64 + fb + 4] = o1;
}

extern "C" void kernel_launch(void* const* d_in, const int* in_sizes, int n_in,
                              void* d_out, int out_size, void* d_ws, size_t ws_size,
                              hipStream_t stream) {
    const float* x     = (const float*)d_in[0];
    const int*   eidx  = (const int*)d_in[1];
    const float* eattr = (const float*)d_in[2];
    const float* W1    = (const float*)d_in[3];
    const float* b1    = (const float*)d_in[4];
    const float* W2    = (const float*)d_in[5];
    const float* b2    = (const float*)d_in[6];
    float* out = (float*)d_out;

    const int n = in_sizes[0] / 128;
    const int E = in_sizes[2];
    const int* row = eidx;
    const int* col = eidx + E;

    const int NBKT = (n + BNODES - 1) / BNODES;    // 196
    const int NEB  = (E + EPB - 1) / EPB;          // 326 (<=512 required)
    const int np16 = n * 16;                       // ushorts per plane

    int2*  sedge1 = (int2*)d_ws;
    int2*  sedge2 = sedge1 + (size_t)E;
    unsigned short* g1 = (unsigned short*)(sedge2 + (size_t)E);
    unsigned short* g2 = g1 + (size_t)n * 64;
    unsigned short* WT1 = g2 + (size_t)n * 64;
    unsigned short* WT2 = WT1 + 64 * 128;
    float* dinv      = (float*)(WT2 + 64 * 64);
    int*   nodeStart = (int*)(dinv + n);
    int*   nodeCnt   = nodeStart + n;
    int*   H         = nodeCnt + n;
    int*   rowSum    = H + (size_t)NEB * NBKT;

    const int nbG  = (n + 63) / 64;
    const int nbG2 = (n + 31) / 32;
    const int NBN  = (n + 127) / 128;              // 782 blocks per plane

    hist_kernel<<<NEB + 48, 256, 0, stream>>>(col, H, E, NBKT, W1, W2, WT1, WT2, NEB);
    rowscan_kernel<<<NBKT, 512, 0, stream>>>(H, rowSum, NEB, NBKT);
    scatter_gemm_kernel<<<NEB + nbG, 256, 0, stream>>>(
        row, col, eattr, H, rowSum, sedge1, E, NBKT, NEB, x, WT1, g1, n, np16);
    fine_dinv_kernel<<<NBKT, 512, 0, stream>>>(sedge1, rowSum, nodeStart, nodeCnt,
                                               dinv, n, NBKT);
    fine_csr_kernel<<<NBKT, 512, 0, stream>>>(sedge1, rowSum, nodeStart, dinv,
                                              sedge2, n, NBKT);

    aggmm_kernel<<<nbG2, 256, 0, stream>>>(g1, sedge2, nodeStart, nodeCnt, dinv,
                                           b1, WT2, g2, n, np16);
    agg_kernel<<<4 * NBN, 256, 0, stream>>>(g2, sedge2, nodeStart, nodeCnt, dinv,
                                            b2, out, n, np16, NBN);
}

// Round 16
// 111.270 us; speedup vs baseline: 1.6840x; 1.6840x over previous
//
#include <hip/hip_runtime.h>

// GCN:  w'_e = dinv[row]*w*dinv[col]  (folded norm, shared by BOTH layers);
//   g = X@W unscaled (MFMA bf16);  out[c] = relu(dinv[c]^2*g[c] + sum w'*g[row] + b)
//
// R16 = R14 (best verified: 108.8us) + 4-deep gather (two int4 descriptor
// loads -> 4 independent row gathers in flight/lane).  R15's plane-slicing
// REVERTED: 32B gathers from 64B lines wasted half the fetch (224MB FETCH);
// full 128B-row gathers are fetch-optimal.  R9's 4-deep failure was an
// occupancy confound (34%, 64-node blocks); here 8-lane/28VGPR is healthy.
// Session facts: global atomic ~62B memory-side; 64M LDS atomics = 445us;
// gathers latency-bound; 32KB LDS cap -> 5 blocks/CU mixed grid.

#define BNODES 512
#define LB 9
#define MAXBKT 256
#define EPT 12
#define EPB (256 * EPT)

typedef __attribute__((ext_vector_type(8))) short bf16x8;
typedef __attribute__((ext_vector_type(8))) unsigned short u16x8;
typedef __attribute__((ext_vector_type(8))) float f32x8;
typedef __attribute__((ext_vector_type(4))) float f32x4;

__device__ __forceinline__ unsigned short f2bf(float f) {
    unsigned u = __float_as_uint(f);
    u = (u + 0x7FFF + ((u >> 16) & 1)) >> 16;   // rtne
    return (unsigned short)u;
}
__device__ __forceinline__ float bf2f(unsigned short h) {
    return __uint_as_float(((unsigned)h) << 16);
}
__device__ __forceinline__ f32x8 bf8tof(u16x8 u) {
    f32x8 r;
    #pragma unroll
    for (int i = 0; i < 8; ++i) r[i] = bf2f(u[i]);
    return r;
}

__device__ __forceinline__ int waveIncScan(int v, int lane) {
    #pragma unroll
    for (int d = 1; d < 64; d <<= 1) {
        int u = __shfl_up(v, d, 64);
        if (lane >= d) v += u;
    }
    return v;
}

template<int NW>
__device__ __forceinline__ int blockIncScan(int v, int t, int* wt) {
    int lane = t & 63, w = t >> 6;
    int s = waveIncScan(v, lane);
    if (lane == 63) wt[w] = s;
    __syncthreads();
    int add = 0;
    #pragma unroll
    for (int i = 0; i < NW - 1; ++i) if (i < w) add += wt[i];
    return s + add;
}

// 8-lane/node gather, 4 edges in flight (two int4 descriptor loads).
__device__ __forceinline__ f32x8 gather8(
    const unsigned short* __restrict__ G, const int2* __restrict__ sedge,
    int s, int m, int p8, f32x8 a0)
{
    f32x8 a1 = (f32x8)0.f, a2 = (f32x8)0.f, a3 = (f32x8)0.f;
    int e = s, e_end = s + m;
    // peel to 16B-aligned pair boundary
    if ((((unsigned long long)(sedge + e)) & 8) && e < e_end) {
        int2 pk = sedge[e++];
        float w = __int_as_float(pk.y);
        a0 += w * bf8tof(*(const u16x8*)&G[(size_t)pk.x * 64 + p8 * 8]);
    }
    for (; e + 3 < e_end; e += 4) {
        int4 pa = *(const int4*)&sedge[e];
        int4 pb = *(const int4*)&sedge[e + 2];
        u16x8 g0 = *(const u16x8*)&G[(size_t)pa.x * 64 + p8 * 8];
        u16x8 g1 = *(const u16x8*)&G[(size_t)pa.z * 64 + p8 * 8];
        u16x8 g2 = *(const u16x8*)&G[(size_t)pb.x * 64 + p8 * 8];
        u16x8 g3 = *(const u16x8*)&G[(size_t)pb.z * 64 + p8 * 8];
        a0 += __int_as_float(pa.y) * bf8tof(g0);
        a1 += __int_as_float(pa.w) * bf8tof(g1);
        a2 += __int_as_float(pb.y) * bf8tof(g2);
        a3 += __int_as_float(pb.w) * bf8tof(g3);
    }
    if (e + 1 < e_end) {
        int4 pa = *(const int4*)&sedge[e];
        u16x8 g0 = *(const u16x8*)&G[(size_t)pa.x * 64 + p8 * 8];
        u16x8 g1 = *(const u16x8*)&G[(size_t)pa.z * 64 + p8 * 8];
        a0 += __int_as_float(pa.y) * bf8tof(g0);
        a1 += __int_as_float(pa.w) * bf8tof(g1);
        e += 2;
    }
    if (e < e_end) {
        int2 pk = sedge[e];
        float w = __int_as_float(pk.y);
        a2 += w * bf8tof(*(const u16x8*)&G[(size_t)pk.x * 64 + p8 * 8]);
    }
    return (a0 + a1) + (a2 + a3);
}

// ---- hist (+ weight transpose in tail blocks) ----------------------------

__global__ __launch_bounds__(256) void hist_kernel(
    const int* __restrict__ col, int* __restrict__ H, int E, int NBKT,
    const float* __restrict__ W1, const float* __restrict__ W2,
    unsigned short* __restrict__ WT1, unsigned short* __restrict__ WT2, int NEB)
{
    int t = threadIdx.x, blk = blockIdx.x;
    if (blk >= NEB) {
        int i = (blk - NEB) * 256 + t;
        if (i < 64 * 128) {
            int c = i >> 7, k = i & 127;
            WT1[i] = f2bf(W1[k * 64 + c]);
        } else if (i < 64 * 128 + 64 * 64) {
            int j = i - 64 * 128;
            int c = j >> 6, k = j & 63;
            WT2[j] = f2bf(W2[k * 64 + c]);
        }
        return;
    }
    __shared__ int h[MAXBKT];
    for (int b = t; b < NBKT; b += 256) h[b] = 0;
    __syncthreads();
    int base = blk * EPB;
    #pragma unroll
    for (int i = 0; i < EPT; ++i) {
        int e = base + i * 256 + t;
        if (e < E) atomicAdd(&h[col[e] >> LB], 1);
    }
    __syncthreads();
    for (int b = t; b < NBKT; b += 256) H[blk * NBKT + b] = h[b];
}

__global__ __launch_bounds__(512) void rowscan_kernel(
    int* __restrict__ H, int* __restrict__ rowSum, int NEB, int NBKT)
{
    __shared__ int wt[8];
    int b = blockIdx.x, t = threadIdx.x;
    int v = (t < NEB) ? H[t * NBKT + b] : 0;
    int incl = blockIncScan<8>(v, t, wt);
    if (t < NEB) H[t * NBKT + b] = incl - v;
    if (t == 511) rowSum[b] = incl;
}

// ---- merged (LDS-sorted scatter) + (layer-1 MFMA GEMM, unscaled) ---------
__global__ __launch_bounds__(256) void scatter_gemm_kernel(
    const int* __restrict__ row, const int* __restrict__ col,
    const float* __restrict__ w, const int* __restrict__ H,
    const int* __restrict__ rowSum, int2* __restrict__ sedge1,
    int E, int NBKT, int NEB,
    const float* __restrict__ X, const unsigned short* __restrict__ WT,
    unsigned short* __restrict__ G, int n)
{
    __shared__ __align__(16) char smem[32768];
    const int t = threadIdx.x;
    const int blk = blockIdx.x;

    if (blk < NEB) {
        int2* stage = (int2*)smem;
        unsigned char* bstage = (unsigned char*)(stage + EPB);
        int* lcnt  = (int*)(bstage + EPB);
        int* loff  = lcnt + MAXBKT;
        int* lcur  = loff + MAXBKT;
        int* gbase = lcur + MAXBKT;
        int* wt    = gbase + MAXBKT;

        int vb = (t < NBKT) ? rowSum[t] : 0;
        int ib = blockIncScan<4>(vb, t, wt);
        if (t < NBKT) gbase[t] = (ib - vb) + H[blk * NBKT + t];
        for (int b = t; b < NBKT; b += 256) lcnt[b] = 0;
        __syncthreads();

        int base = blk * EPB;
        #pragma unroll
        for (int i = 0; i < EPT; ++i) {
            int e = base + i * 256 + t;
            if (e < E) atomicAdd(&lcnt[col[e] >> LB], 1);
        }
        __syncthreads();
        int v = (t < NBKT) ? lcnt[t] : 0;
        int incl = blockIncScan<4>(v, t, wt);
        if (t < NBKT) {
            int x0 = incl - v;
            loff[t] = x0;
            lcur[t] = x0;
        }
        __syncthreads();
        #pragma unroll
        for (int i = 0; i < EPT; ++i) {
            int e = base + i * 256 + t;
            if (e < E) {
                int c = col[e];
                int b = c >> LB;
                int pos = atomicAdd(&lcur[b], 1);    // LDS atomic
                int2 pk;
                pk.x = row[e] | ((c & (BNODES - 1)) << 20);
                pk.y = __float_as_int(w[e]);
                stage[pos] = pk;
                bstage[pos] = (unsigned char)b;
            }
        }
        __syncthreads();
        int ecnt = E - base; if (ecnt > EPB) ecnt = EPB;
        for (int i = t; i < ecnt; i += 256) {
            int b = bstage[i];
            int g = gbase[b] + (i - loff[b]);
            sedge1[g] = stage[i];
        }
        return;
    }

    constexpr int K = 128, ROWB = 256, SLOTS = 16, CPR = 32;
    char* xs = smem;
    char* ws = smem + 64 * ROWB;
    const int nodeBase = (blk - NEB) * 64;

    for (int q = t; q < 64 * SLOTS; q += 256) {
        int r = q / SLOTS, s = q % SLOTS;
        uint4 v = *(const uint4*)(WT + r * K + s * 8);
        *(uint4*)(ws + r * ROWB + ((s ^ (r & 7)) * 16)) = v;
    }
    for (int q = t; q < 64 * CPR; q += 256) {
        int r = q / CPR, c = q % CPR;
        int node = nodeBase + r;
        float4 v = make_float4(0.f, 0.f, 0.f, 0.f);
        if (node < n) v = *(const float4*)(X + (size_t)node * K + c * 4);
        ushort4 h;
        h.x = f2bf(v.x); h.y = f2bf(v.y); h.z = f2bf(v.z); h.w = f2bf(v.w);
        *(ushort4*)(xs + r * ROWB + (((c >> 1) ^ (r & 7)) * 16) + (c & 1) * 8) = h;
    }
    __syncthreads();

    const int lane = t & 63;
    const int wv = t >> 6;
    const int lr = lane & 15;
    const int lk = lane >> 4;
    const int arow = (wv << 4) + lr;

    f32x4 acc[4] = {};
    #pragma unroll
    for (int kb = 0; kb < 4; ++kb) {
        int s = kb * 4 + lk;
        bf16x8 a = *(bf16x8*)(xs + arow * ROWB + ((s ^ (arow & 7)) * 16));
        #pragma unroll
        for (int cb = 0; cb < 4; ++cb) {
            int c = cb * 16 + lr;
            bf16x8 b = *(bf16x8*)(ws + c * ROWB + ((s ^ (c & 7)) * 16));
            acc[cb] = __builtin_amdgcn_mfma_f32_16x16x32_bf16(a, b, acc[cb], 0, 0, 0);
        }
    }

    int rowbase = nodeBase + (wv << 4) + (lk << 2);
    #pragma unroll
    for (int j = 0; j < 4; ++j) {
        int node = rowbase + j;
        if (node >= n) continue;
        #pragma unroll
        for (int cb = 0; cb < 4; ++cb)
            G[(size_t)node * 64 + cb * 16 + lr] = f2bf(acc[cb][j]);
    }
}

// ---- fine_dinv: per-bucket degree + scan -> nodeStart/nodeCnt/dinv -------
__global__ __launch_bounds__(512) void fine_dinv_kernel(
    const int2* __restrict__ sedge1, const int* __restrict__ rowSum,
    int* __restrict__ nodeStart, int* __restrict__ nodeCnt,
    float* __restrict__ dinv, int n, int NBKT)
{
    __shared__ int cnt[BNODES];
    __shared__ float wsum[BNODES];
    __shared__ int bs[MAXBKT + 1];
    __shared__ int wt[8];
    int b = blockIdx.x, t = threadIdx.x;

    int vb = (t < NBKT) ? rowSum[t] : 0;
    int ib = blockIncScan<8>(vb, t, wt);
    if (t < NBKT) bs[t] = ib - vb;
    if (t == 511) bs[NBKT] = ib;
    cnt[t] = 0; wsum[t] = 1.0f;
    __syncthreads();

    int s = bs[b], e = bs[b + 1];
    for (int j = s + t; j < e; j += 512) {
        int2 pk = sedge1[j];
        int ld = pk.x >> 20;
        atomicAdd(&cnt[ld], 1);
        atomicAdd(&wsum[ld], __int_as_float(pk.y));
    }
    __syncthreads();
    int v = cnt[t];
    int incl = blockIncScan<8>(v, t, wt);
    int x0 = s + incl - v;
    int node = b * BNODES + t;
    if (node < n) {
        nodeStart[node] = x0;
        nodeCnt[node] = v;
        dinv[node] = rsqrtf(wsum[t]);
    }
}

// ---- fine_csr: CSR scatter with folded weights w' = dinv[row]*w*dinv[col] -
__global__ __launch_bounds__(512) void fine_csr_kernel(
    const int2* __restrict__ sedge1, const int* __restrict__ rowSum,
    const int* __restrict__ nodeStart, const float* __restrict__ dinv,
    int2* __restrict__ sedge2, int n, int NBKT)
{
    __shared__ int cur[BNODES];
    __shared__ float dloc[BNODES];
    __shared__ int bs[MAXBKT + 1];
    __shared__ int wt[8];
    int b = blockIdx.x, t = threadIdx.x;

    int vb = (t < NBKT) ? rowSum[t] : 0;
    int ib = blockIncScan<8>(vb, t, wt);
    if (t < NBKT) bs[t] = ib - vb;
    if (t == 511) bs[NBKT] = ib;
    int node = b * BNODES + t;
    cur[t]  = (node < n) ? nodeStart[node] : 0;
    dloc[t] = (node < n) ? dinv[node] : 0.f;
    __syncthreads();

    int s = bs[b], e = bs[b + 1];
    for (int j = s + t; j < e; j += 512) {
        int2 pk = sedge1[j];
        int ld = pk.x >> 20;
        int rw = pk.x & 0xFFFFF;
        int pos = atomicAdd(&cur[ld], 1);            // LDS atomic
        float wp = __int_as_float(pk.y) * dinv[rw] * dloc[ld];
        sedge2[pos] = make_int2(rw, __float_as_int(wp));
    }
}

// ---- FUSED agg1 + gemm2, 32 nodes/block, single-pass 8-lane agg ----------
__global__ __launch_bounds__(256) void aggmm_kernel(
    const unsigned short* __restrict__ G1, const int2* __restrict__ sedge2,
    const int* __restrict__ nodeStart, const int* __restrict__ nodeCnt,
    const float* __restrict__ dinv, const float* __restrict__ bias,
    const unsigned short* __restrict__ WT2, unsigned short* __restrict__ G2, int n)
{
    constexpr int BN = 32;
    constexpr int ROWB = 128;
    __shared__ char smem[(BN + 64) * ROWB];   // act (4KB) | ws (8KB)
    char* xs = smem;
    char* ws = smem + BN * ROWB;
    const int tid = threadIdx.x;
    const int nodeBase = blockIdx.x * BN;

    for (int q = tid; q < 64 * 8; q += 256) {
        int r = q >> 3, s = q & 7;
        uint4 v = *(const uint4*)(WT2 + r * 64 + s * 8);
        *(uint4*)(ws + r * ROWB + ((s ^ (r & 7)) * 16)) = v;
    }

    int p8 = tid & 7;
    int r = tid >> 3;
    int node = nodeBase + r;
    f32x8 o = (f32x8)0.f;
    if (node < n) {
        float di = dinv[node];
        f32x8 a = (di * di) * bf8tof(*(const u16x8*)&G1[(size_t)node * 64 + p8 * 8]);
        a = gather8(G1, sedge2, nodeStart[node], nodeCnt[node], p8, a);
        #pragma unroll
        for (int i = 0; i < 8; ++i)
            o[i] = fmaxf(a[i] + bias[p8 * 8 + i], 0.f);
    }
    u16x8 h;
    #pragma unroll
    for (int i = 0; i < 8; ++i) h[i] = f2bf(o[i]);
    *(u16x8*)(xs + r * ROWB + ((p8 ^ (r & 7)) * 16)) = h;
    __syncthreads();

    const int lane = tid & 63;
    const int w = tid >> 6;
    const int lr = lane & 15;
    const int lk = lane >> 4;
    const int rb = w >> 1;
    const int arow = rb * 16 + lr;

    f32x4 acc[2] = {};
    #pragma unroll
    for (int kb = 0; kb < 2; ++kb) {
        int s = kb * 4 + lk;
        bf16x8 a = *(bf16x8*)(xs + arow * ROWB + ((s ^ (arow & 7)) * 16));
        #pragma unroll
        for (int cc = 0; cc < 2; ++cc) {
            int c = ((w & 1) * 2 + cc) * 16 + lr;
            bf16x8 b = *(bf16x8*)(ws + c * ROWB + ((s ^ (c & 7)) * 16));
            acc[cc] = __builtin_amdgcn_mfma_f32_16x16x32_bf16(a, b, acc[cc], 0, 0, 0);
        }
    }

    // g2 written UNSCALED (normalization folded into w' and self-term)
    int rowbase = nodeBase + rb * 16 + (lk << 2);
    #pragma unroll
    for (int j = 0; j < 4; ++j) {
        int nd = rowbase + j;
        if (nd >= n) continue;
        #pragma unroll
        for (int cc = 0; cc < 2; ++cc)
            G2[(size_t)nd * 64 + ((w & 1) * 2 + cc) * 16 + lr] = f2bf(acc[cc][j]);
    }
}

// ---- final aggregation (f32 out), 8 lanes/node ---------------------------
__global__ __launch_bounds__(256) void agg_kernel(
    const unsigned short* __restrict__ G, const int2* __restrict__ sedge2,
    const int* __restrict__ nodeStart, const int* __restrict__ nodeCnt,
    const float* __restrict__ dinv, const float* __restrict__ bias,
    float* __restrict__ OUT, int n)
{
    int t = blockIdx.x * blockDim.x + threadIdx.x;
    if (t >= n * 8) return;
    int node = t >> 3, p8 = t & 7;

    float di = dinv[node];
    f32x8 a = (di * di) * bf8tof(*(const u16x8*)&G[(size_t)node * 64 + p8 * 8]);
    a = gather8(G, sedge2, nodeStart[node], nodeCnt[node], p8, a);

    float4 o0, o1;
    o0.x = fmaxf(a[0] + bias[p8 * 8 + 0], 0.f);
    o0.y = fmaxf(a[1] + bias[p8 * 8 + 1], 0.f);
    o0.z = fmaxf(a[2] + bias[p8 * 8 + 2], 0.f);
    o0.w = fmaxf(a[3] + bias[p8 * 8 + 3], 0.f);
    o1.x = fmaxf(a[4] + bias[p8 * 8 + 4], 0.f);
    o1.y = fmaxf(a[5] + bias[p8 * 8 + 5], 0.f);
    o1.z = fmaxf(a[6] + bias[p8 * 8 + 6], 0.f);
    o1.w = fmaxf(a[7] + bias[p8 * 8 + 7], 0.f);
    *(float4*)&OUT[(size_t)node * 64 + p8 * 8] = o0;
    *(float4*)&OUT[(size_t)node * 64 + p8 * 8 + 4] = o1;
}

extern "C" void kernel_launch(void* const* d_in, const int* in_sizes, int n_in,
                              void* d_out, int out_size, void* d_ws, size_t ws_size,
                              hipStream_t stream) {
    const float* x     = (const float*)d_in[0];
    const int*   eidx  = (const int*)d_in[1];
    const float* eattr = (const float*)d_in[2];
    const float* W1    = (const float*)d_in[3];
    const float* b1    = (const float*)d_in[4];
    const float* W2    = (const float*)d_in[5];
    const float* b2    = (const float*)d_in[6];
    float* out = (float*)d_out;

    const int n = in_sizes[0] / 128;
    const int E = in_sizes[2];
    const int* row = eidx;
    const int* col = eidx + E;

    const int NBKT = (n + BNODES - 1) / BNODES;    // 196
    const int NEB  = (E + EPB - 1) / EPB;          // 326 (<=512 required)

    int2*  sedge1 = (int2*)d_ws;
    int2*  sedge2 = sedge1 + (size_t)E;
    unsigned short* g1 = (unsigned short*)(sedge2 + (size_t)E);
    unsigned short* g2 = g1 + (size_t)n * 64;
    unsigned short* WT1 = g2 + (size_t)n * 64;
    unsigned short* WT2 = WT1 + 64 * 128;
    float* dinv      = (float*)(WT2 + 64 * 64);
    int*   nodeStart = (int*)(dinv + n);
    int*   nodeCnt   = nodeStart + n;
    int*   H         = nodeCnt + n;
    int*   rowSum    = H + (size_t)NEB * NBKT;

    const int nbG  = (n + 63) / 64;
    const int nbG2 = (n + 31) / 32;
    const int nbA8 = (int)(((size_t)n * 8 + 255) / 256);

    hist_kernel<<<NEB + 48, 256, 0, stream>>>(col, H, E, NBKT, W1, W2, WT1, WT2, NEB);
    rowscan_kernel<<<NBKT, 512, 0, stream>>>(H, rowSum, NEB, NBKT);
    scatter_gemm_kernel<<<NEB + nbG, 256, 0, stream>>>(
        row, col, eattr, H, rowSum, sedge1, E, NBKT, NEB, x, WT1, g1, n);
    fine_dinv_kernel<<<NBKT, 512, 0, stream>>>(sedge1, rowSum, nodeStart, nodeCnt,
                                               dinv, n, NBKT);
    fine_csr_kernel<<<NBKT, 512, 0, stream>>>(sedge1, rowSum, nodeStart, dinv,
                                              sedge2, n, NBKT);

    aggmm_kernel<<<nbG2, 256, 0, stream>>>(g1, sedge2, nodeStart, nodeCnt, dinv, b1, WT2, g2, n);
    agg_kernel<<<nbA8, 256, 0, stream>>>(g2, sedge2, nodeStart, nodeCnt, dinv, b2, out, n);
}

// Round 17
// 109.246 us; speedup vs baseline: 1.7152x; 1.0185x over previous
//
#include <hip/hip_runtime.h>

// GCN:  w'_e = dinv[row]*w*dinv[col]  (folded norm, shared by BOTH layers);
//   g = X@W unscaled (MFMA bf16);  out[c] = relu(dinv[c]^2*g[c] + sum w'*g[row] + b)
//
// R17 = exact R14 revert (best verified: 108.84us).  Final structure:
//  - counting-sort -> CSR build, ZERO global data atomics (measured: each
//    global atomic costs ~62B memory-side traffic; 64M LDS atomics = 445us)
//  - layer-1 MFMA GEMM rides on scatter's launch (no dinv dependency)
//  - agg1+gemm2 fused (activation only in LDS), 32-node blocks (occupancy)
//  - gathers: 8 lanes/node x ushort8 (16B/lane), int4 descriptor pairs,
//    2-deep MLP.  4-deep is neutral-to-worse (R9, R16); plane-slicing is
//    2x worse (R15: 32B gathers waste half of each 64B line).  The gathers
//    run at ~5.6TB/s effective random-access — the structure's floor.

#define BNODES 512
#define LB 9
#define MAXBKT 256
#define EPT 12
#define EPB (256 * EPT)

typedef __attribute__((ext_vector_type(8))) short bf16x8;
typedef __attribute__((ext_vector_type(8))) unsigned short u16x8;
typedef __attribute__((ext_vector_type(8))) float f32x8;
typedef __attribute__((ext_vector_type(4))) float f32x4;

__device__ __forceinline__ unsigned short f2bf(float f) {
    unsigned u = __float_as_uint(f);
    u = (u + 0x7FFF + ((u >> 16) & 1)) >> 16;   // rtne
    return (unsigned short)u;
}
__device__ __forceinline__ float bf2f(unsigned short h) {
    return __uint_as_float(((unsigned)h) << 16);
}
__device__ __forceinline__ f32x8 bf8tof(u16x8 u) {
    f32x8 r;
    #pragma unroll
    for (int i = 0; i < 8; ++i) r[i] = bf2f(u[i]);
    return r;
}

__device__ __forceinline__ int waveIncScan(int v, int lane) {
    #pragma unroll
    for (int d = 1; d < 64; d <<= 1) {
        int u = __shfl_up(v, d, 64);
        if (lane >= d) v += u;
    }
    return v;
}

template<int NW>
__device__ __forceinline__ int blockIncScan(int v, int t, int* wt) {
    int lane = t & 63, w = t >> 6;
    int s = waveIncScan(v, lane);
    if (lane == 63) wt[w] = s;
    __syncthreads();
    int add = 0;
    #pragma unroll
    for (int i = 0; i < NW - 1; ++i) if (i < w) add += wt[i];
    return s + add;
}

// 8-lane/node gather: descriptor pairs via int4, rows via ushort8, 2-deep.
__device__ __forceinline__ f32x8 gather8(
    const unsigned short* __restrict__ G, const int2* __restrict__ sedge,
    int s, int m, int p8, f32x8 a0)
{
    f32x8 a1 = (f32x8)0.f;
    int e = s, e_end = s + m;
    if ((((unsigned long long)(sedge + e)) & 8) && e < e_end) {
        int2 pk = sedge[e++];
        float w = __int_as_float(pk.y);
        a0 += w * bf8tof(*(const u16x8*)&G[(size_t)pk.x * 64 + p8 * 8]);
    }
    for (; e + 1 < e_end; e += 2) {
        int4 pp = *(const int4*)&sedge[e];
        float w0 = __int_as_float(pp.y);
        float w1 = __int_as_float(pp.w);
        u16x8 g0 = *(const u16x8*)&G[(size_t)pp.x * 64 + p8 * 8];
        u16x8 g1 = *(const u16x8*)&G[(size_t)pp.z * 64 + p8 * 8];
        a0 += w0 * bf8tof(g0);
        a1 += w1 * bf8tof(g1);
    }
    if (e < e_end) {
        int2 pk = sedge[e];
        float w = __int_as_float(pk.y);
        a0 += w * bf8tof(*(const u16x8*)&G[(size_t)pk.x * 64 + p8 * 8]);
    }
    return a0 + a1;
}

// ---- hist (+ weight transpose in tail blocks) ----------------------------

__global__ __launch_bounds__(256) void hist_kernel(
    const int* __restrict__ col, int* __restrict__ H, int E, int NBKT,
    const float* __restrict__ W1, const float* __restrict__ W2,
    unsigned short* __restrict__ WT1, unsigned short* __restrict__ WT2, int NEB)
{
    int t = threadIdx.x, blk = blockIdx.x;
    if (blk >= NEB) {
        int i = (blk - NEB) * 256 + t;
        if (i < 64 * 128) {
            int c = i >> 7, k = i & 127;
            WT1[i] = f2bf(W1[k * 64 + c]);
        } else if (i < 64 * 128 + 64 * 64) {
            int j = i - 64 * 128;
            int c = j >> 6, k = j & 63;
            WT2[j] = f2bf(W2[k * 64 + c]);
        }
        return;
    }
    __shared__ int h[MAXBKT];
    for (int b = t; b < NBKT; b += 256) h[b] = 0;
    __syncthreads();
    int base = blk * EPB;
    #pragma unroll
    for (int i = 0; i < EPT; ++i) {
        int e = base + i * 256 + t;
        if (e < E) atomicAdd(&h[col[e] >> LB], 1);
    }
    __syncthreads();
    for (int b = t; b < NBKT; b += 256) H[blk * NBKT + b] = h[b];
}

__global__ __launch_bounds__(512) void rowscan_kernel(
    int* __restrict__ H, int* __restrict__ rowSum, int NEB, int NBKT)
{
    __shared__ int wt[8];
    int b = blockIdx.x, t = threadIdx.x;
    int v = (t < NEB) ? H[t * NBKT + b] : 0;
    int incl = blockIncScan<8>(v, t, wt);
    if (t < NEB) H[t * NBKT + b] = incl - v;
    if (t == 511) rowSum[b] = incl;
}

// ---- merged (LDS-sorted scatter) + (layer-1 MFMA GEMM, unscaled) ---------
__global__ __launch_bounds__(256) void scatter_gemm_kernel(
    const int* __restrict__ row, const int* __restrict__ col,
    const float* __restrict__ w, const int* __restrict__ H,
    const int* __restrict__ rowSum, int2* __restrict__ sedge1,
    int E, int NBKT, int NEB,
    const float* __restrict__ X, const unsigned short* __restrict__ WT,
    unsigned short* __restrict__ G, int n)
{
    __shared__ __align__(16) char smem[32768];
    const int t = threadIdx.x;
    const int blk = blockIdx.x;

    if (blk < NEB) {
        int2* stage = (int2*)smem;
        unsigned char* bstage = (unsigned char*)(stage + EPB);
        int* lcnt  = (int*)(bstage + EPB);
        int* loff  = lcnt + MAXBKT;
        int* lcur  = loff + MAXBKT;
        int* gbase = lcur + MAXBKT;
        int* wt    = gbase + MAXBKT;

        int vb = (t < NBKT) ? rowSum[t] : 0;
        int ib = blockIncScan<4>(vb, t, wt);
        if (t < NBKT) gbase[t] = (ib - vb) + H[blk * NBKT + t];
        for (int b = t; b < NBKT; b += 256) lcnt[b] = 0;
        __syncthreads();

        int base = blk * EPB;
        #pragma unroll
        for (int i = 0; i < EPT; ++i) {
            int e = base + i * 256 + t;
            if (e < E) atomicAdd(&lcnt[col[e] >> LB], 1);
        }
        __syncthreads();
        int v = (t < NBKT) ? lcnt[t] : 0;
        int incl = blockIncScan<4>(v, t, wt);
        if (t < NBKT) {
            int x0 = incl - v;
            loff[t] = x0;
            lcur[t] = x0;
        }
        __syncthreads();
        #pragma unroll
        for (int i = 0; i < EPT; ++i) {
            int e = base + i * 256 + t;
            if (e < E) {
                int c = col[e];
                int b = c >> LB;
                int pos = atomicAdd(&lcur[b], 1);    // LDS atomic
                int2 pk;
                pk.x = row[e] | ((c & (BNODES - 1)) << 20);
                pk.y = __float_as_int(w[e]);
                stage[pos] = pk;
                bstage[pos] = (unsigned char)b;
            }
        }
        __syncthreads();
        int ecnt = E - base; if (ecnt > EPB) ecnt = EPB;
        for (int i = t; i < ecnt; i += 256) {
            int b = bstage[i];
            int g = gbase[b] + (i - loff[b]);
            sedge1[g] = stage[i];
        }
        return;
    }

    constexpr int K = 128, ROWB = 256, SLOTS = 16, CPR = 32;
    char* xs = smem;
    char* ws = smem + 64 * ROWB;
    const int nodeBase = (blk - NEB) * 64;

    for (int q = t; q < 64 * SLOTS; q += 256) {
        int r = q / SLOTS, s = q % SLOTS;
        uint4 v = *(const uint4*)(WT + r * K + s * 8);
        *(uint4*)(ws + r * ROWB + ((s ^ (r & 7)) * 16)) = v;
    }
    for (int q = t; q < 64 * CPR; q += 256) {
        int r = q / CPR, c = q % CPR;
        int node = nodeBase + r;
        float4 v = make_float4(0.f, 0.f, 0.f, 0.f);
        if (node < n) v = *(const float4*)(X + (size_t)node * K + c * 4);
        ushort4 h;
        h.x = f2bf(v.x); h.y = f2bf(v.y); h.z = f2bf(v.z); h.w = f2bf(v.w);
        *(ushort4*)(xs + r * ROWB + (((c >> 1) ^ (r & 7)) * 16) + (c & 1) * 8) = h;
    }
    __syncthreads();

    const int lane = t & 63;
    const int wv = t >> 6;
    const int lr = lane & 15;
    const int lk = lane >> 4;
    const int arow = (wv << 4) + lr;

    f32x4 acc[4] = {};
    #pragma unroll
    for (int kb = 0; kb < 4; ++kb) {
        int s = kb * 4 + lk;
        bf16x8 a = *(bf16x8*)(xs + arow * ROWB + ((s ^ (arow & 7)) * 16));
        #pragma unroll
        for (int cb = 0; cb < 4; ++cb) {
            int c = cb * 16 + lr;
            bf16x8 b = *(bf16x8*)(ws + c * ROWB + ((s ^ (c & 7)) * 16));
            acc[cb] = __builtin_amdgcn_mfma_f32_16x16x32_bf16(a, b, acc[cb], 0, 0, 0);
        }
    }

    int rowbase = nodeBase + (wv << 4) + (lk << 2);
    #pragma unroll
    for (int j = 0; j < 4; ++j) {
        int node = rowbase + j;
        if (node >= n) continue;
        #pragma unroll
        for (int cb = 0; cb < 4; ++cb)
            G[(size_t)node * 64 + cb * 16 + lr] = f2bf(acc[cb][j]);
    }
}

// ---- fine_dinv: per-bucket degree + scan -> nodeStart/nodeCnt/dinv -------
__global__ __launch_bounds__(512) void fine_dinv_kernel(
    const int2* __restrict__ sedge1, const int* __restrict__ rowSum,
    int* __restrict__ nodeStart, int* __restrict__ nodeCnt,
    float* __restrict__ dinv, int n, int NBKT)
{
    __shared__ int cnt[BNODES];
    __shared__ float wsum[BNODES];
    __shared__ int bs[MAXBKT + 1];
    __shared__ int wt[8];
    int b = blockIdx.x, t = threadIdx.x;

    int vb = (t < NBKT) ? rowSum[t] : 0;
    int ib = blockIncScan<8>(vb, t, wt);
    if (t < NBKT) bs[t] = ib - vb;
    if (t == 511) bs[NBKT] = ib;
    cnt[t] = 0; wsum[t] = 1.0f;
    __syncthreads();

    int s = bs[b], e = bs[b + 1];
    for (int j = s + t; j < e; j += 512) {
        int2 pk = sedge1[j];
        int ld = pk.x >> 20;
        atomicAdd(&cnt[ld], 1);
        atomicAdd(&wsum[ld], __int_as_float(pk.y));
    }
    __syncthreads();
    int v = cnt[t];
    int incl = blockIncScan<8>(v, t, wt);
    int x0 = s + incl - v;
    int node = b * BNODES + t;
    if (node < n) {
        nodeStart[node] = x0;
        nodeCnt[node] = v;
        dinv[node] = rsqrtf(wsum[t]);
    }
}

// ---- fine_csr: CSR scatter with folded weights w' = dinv[row]*w*dinv[col] -
__global__ __launch_bounds__(512) void fine_csr_kernel(
    const int2* __restrict__ sedge1, const int* __restrict__ rowSum,
    const int* __restrict__ nodeStart, const float* __restrict__ dinv,
    int2* __restrict__ sedge2, int n, int NBKT)
{
    __shared__ int cur[BNODES];
    __shared__ float dloc[BNODES];
    __shared__ int bs[MAXBKT + 1];
    __shared__ int wt[8];
    int b = blockIdx.x, t = threadIdx.x;

    int vb = (t < NBKT) ? rowSum[t] : 0;
    int ib = blockIncScan<8>(vb, t, wt);
    if (t < NBKT) bs[t] = ib - vb;
    if (t == 511) bs[NBKT] = ib;
    int node = b * BNODES + t;
    cur[t]  = (node < n) ? nodeStart[node] : 0;
    dloc[t] = (node < n) ? dinv[node] : 0.f;
    __syncthreads();

    int s = bs[b], e = bs[b + 1];
    for (int j = s + t; j < e; j += 512) {
        int2 pk = sedge1[j];
        int ld = pk.x >> 20;
        int rw = pk.x & 0xFFFFF;
        int pos = atomicAdd(&cur[ld], 1);            // LDS atomic
        float wp = __int_as_float(pk.y) * dinv[rw] * dloc[ld];
        sedge2[pos] = make_int2(rw, __float_as_int(wp));
    }
}

// ---- FUSED agg1 + gemm2, 32 nodes/block, single-pass 8-lane agg ----------
__global__ __launch_bounds__(256) void aggmm_kernel(
    const unsigned short* __restrict__ G1, const int2* __restrict__ sedge2,
    const int* __restrict__ nodeStart, const int* __restrict__ nodeCnt,
    const float* __restrict__ dinv, const float* __restrict__ bias,
    const unsigned short* __restrict__ WT2, unsigned short* __restrict__ G2, int n)
{
    constexpr int BN = 32;
    constexpr int ROWB = 128;
    __shared__ char smem[(BN + 64) * ROWB];   // act (4KB) | ws (8KB)
    char* xs = smem;
    char* ws = smem + BN * ROWB;
    const int tid = threadIdx.x;
    const int nodeBase = blockIdx.x * BN;

    for (int q = tid; q < 64 * 8; q += 256) {
        int r = q >> 3, s = q & 7;
        uint4 v = *(const uint4*)(WT2 + r * 64 + s * 8);
        *(uint4*)(ws + r * ROWB + ((s ^ (r & 7)) * 16)) = v;
    }

    int p8 = tid & 7;
    int r = tid >> 3;
    int node = nodeBase + r;
    f32x8 o = (f32x8)0.f;
    if (node < n) {
        float di = dinv[node];
        f32x8 a = (di * di) * bf8tof(*(const u16x8*)&G1[(size_t)node * 64 + p8 * 8]);
        a = gather8(G1, sedge2, nodeStart[node], nodeCnt[node], p8, a);
        #pragma unroll
        for (int i = 0; i < 8; ++i)
            o[i] = fmaxf(a[i] + bias[p8 * 8 + i], 0.f);
    }
    u16x8 h;
    #pragma unroll
    for (int i = 0; i < 8; ++i) h[i] = f2bf(o[i]);
    *(u16x8*)(xs + r * ROWB + ((p8 ^ (r & 7)) * 16)) = h;
    __syncthreads();

    const int lane = tid & 63;
    const int w = tid >> 6;
    const int lr = lane & 15;
    const int lk = lane >> 4;
    const int rb = w >> 1;
    const int arow = rb * 16 + lr;

    f32x4 acc[2] = {};
    #pragma unroll
    for (int kb = 0; kb < 2; ++kb) {
        int s = kb * 4 + lk;
        bf16x8 a = *(bf16x8*)(xs + arow * ROWB + ((s ^ (arow & 7)) * 16));
        #pragma unroll
        for (int cc = 0; cc < 2; ++cc) {
            int c = ((w & 1) * 2 + cc) * 16 + lr;
            bf16x8 b = *(bf16x8*)(ws + c * ROWB + ((s ^ (c & 7)) * 16));
            acc[cc] = __builtin_amdgcn_mfma_f32_16x16x32_bf16(a, b, acc[cc], 0, 0, 0);
        }
    }

    // g2 written UNSCALED (normalization folded into w' and self-term)
    int rowbase = nodeBase + rb * 16 + (lk << 2);
    #pragma unroll
    for (int j = 0; j < 4; ++j) {
        int nd = rowbase + j;
        if (nd >= n) continue;
        #pragma unroll
        for (int cc = 0; cc < 2; ++cc)
            G2[(size_t)nd * 64 + ((w & 1) * 2 + cc) * 16 + lr] = f2bf(acc[cc][j]);
    }
}

// ---- final aggregation (f32 out), 8 lanes/node ---------------------------
__global__ __launch_bounds__(256) void agg_kernel(
    const unsigned short* __restrict__ G, const int2* __restrict__ sedge2,
    const int* __restrict__ nodeStart, const int* __restrict__ nodeCnt,
    const float* __restrict__ dinv, const float* __restrict__ bias,
    float* __restrict__ OUT, int n)
{
    int t = blockIdx.x * blockDim.x + threadIdx.x;
    if (t >= n * 8) return;
    int node = t >> 3, p8 = t & 7;

    float di = dinv[node];
    f32x8 a = (di * di) * bf8tof(*(const u16x8*)&G[(size_t)node * 64 + p8 * 8]);
    a = gather8(G, sedge2, nodeStart[node], nodeCnt[node], p8, a);

    float4 o0, o1;
    o0.x = fmaxf(a[0] + bias[p8 * 8 + 0], 0.f);
    o0.y = fmaxf(a[1] + bias[p8 * 8 + 1], 0.f);
    o0.z = fmaxf(a[2] + bias[p8 * 8 + 2], 0.f);
    o0.w = fmaxf(a[3] + bias[p8 * 8 + 3], 0.f);
    o1.x = fmaxf(a[4] + bias[p8 * 8 + 4], 0.f);
    o1.y = fmaxf(a[5] + bias[p8 * 8 + 5], 0.f);
    o1.z = fmaxf(a[6] + bias[p8 * 8 + 6], 0.f);
    o1.w = fmaxf(a[7] + bias[p8 * 8 + 7], 0.f);
    *(float4*)&OUT[(size_t)node * 64 + p8 * 8] = o0;
    *(float4*)&OUT[(size_t)node * 64 + p8 * 8 + 4] = o1;
}

extern "C" void kernel_launch(void* const* d_in, const int* in_sizes, int n_in,
                              void* d_out, int out_size, void* d_ws, size_t ws_size,
                              hipStream_t stream) {
    const float* x     = (const float*)d_in[0];
    const int*   eidx  = (const int*)d_in[1];
    const float* eattr = (const float*)d_in[2];
    const float* W1    = (const float*)d_in[3];
    const float* b1    = (const float*)d_in[4];
    const float* W2    = (const float*)d_in[5];
    const float* b2    = (const float*)d_in[6];
    float* out = (float*)d_out;

    const int n = in_sizes[0] / 128;
    const int E = in_sizes[2];
    const int* row = eidx;
    const int* col = eidx + E;

    const int NBKT = (n + BNODES - 1) / BNODES;    // 196
    const int NEB  = (E + EPB - 1) / EPB;          // 326 (<=512 required)

    int2*  sedge1 = (int2*)d_ws;
    int2*  sedge2 = sedge1 + (size_t)E;
    unsigned short* g1 = (unsigned short*)(sedge2 + (size_t)E);
    unsigned short* g2 = g1 + (size_t)n * 64;
    unsigned short* WT1 = g2 + (size_t)n * 64;
    unsigned short* WT2 = WT1 + 64 * 128;
    float* dinv      = (float*)(WT2 + 64 * 64);
    int*   nodeStart = (int*)(dinv + n);
    int*   nodeCnt   = nodeStart + n;
    int*   H         = nodeCnt + n;
    int*   rowSum    = H + (size_t)NEB * NBKT;

    const int nbG  = (n + 63) / 64;
    const int nbG2 = (n + 31) / 32;
    const int nbA8 = (int)(((size_t)n * 8 + 255) / 256);

    hist_kernel<<<NEB + 48, 256, 0, stream>>>(col, H, E, NBKT, W1, W2, WT1, WT2, NEB);
    rowscan_kernel<<<NBKT, 512, 0, stream>>>(H, rowSum, NEB, NBKT);
    scatter_gemm_kernel<<<NEB + nbG, 256, 0, stream>>>(
        row, col, eattr, H, rowSum, sedge1, E, NBKT, NEB, x, WT1, g1, n);
    fine_dinv_kernel<<<NBKT, 512, 0, stream>>>(sedge1, rowSum, nodeStart, nodeCnt,
                                               dinv, n, NBKT);
    fine_csr_kernel<<<NBKT, 512, 0, stream>>>(sedge1, rowSum, nodeStart, dinv,
                                              sedge2, n, NBKT);

    aggmm_kernel<<<nbG2, 256, 0, stream>>>(g1, sedge2, nodeStart, nodeCnt, dinv, b1, WT2, g2, n);
    agg_kernel<<<nbA8, 256, 0, stream>>>(g2, sedge2, nodeStart, nodeCnt, dinv, b2, out, n);
}